// Round 6
// baseline (273.391 us; speedup 1.0000x reference)
//
#include <hip/hip_runtime.h>
#include <math.h>

// N=262144, D=128, C=1024. Embeddings fp32, output fp32 scalar, labels int32
// (int64 tolerated via uniform high-word probe). Strategy: counting-sort ranks,
// then a SEQUENTIAL-read pass normalizes rows and scatter-WRITES them (bf16)
// into class-sorted order (writes don't stall), then per-class sums read
// CONTIGUOUS memory. This removes the random-gather latency chain that capped
// R5's class_sum at ~5.5 GB/s/CU.
#define NUM_CLASSES 1024
#define HIST_CHUNK 2048
#define NB 128                      // hist/rank blocks

__device__ __forceinline__ int detect_mode32(const int* __restrict__ l) {
    return (l[1] | l[3] | l[5] | l[7] | l[9] | l[11] | l[13] | l[15]) != 0;
}
__device__ __forceinline__ int get_label(const int* __restrict__ l, int i, int mode32) {
    return l[mode32 ? i : (i << 1)] & (NUM_CLASSES - 1);
}
__device__ __forceinline__ unsigned bf16rne(float x) {
    unsigned u = __float_as_uint(x);
    return (u + 0x7FFFu + ((u >> 16) & 1u)) >> 16;
}
__device__ __forceinline__ unsigned packbf(float a, float b) {
    return bf16rne(a) | (bf16rne(b) << 16);
}
__device__ __forceinline__ float unpack_lo(unsigned u) { return __uint_as_float(u << 16); }
__device__ __forceinline__ float unpack_hi(unsigned u) { return __uint_as_float(u & 0xffff0000u); }

// ---------------- Kernel 1: per-block partial histograms ----------------
__global__ void hist_kernel(const int* __restrict__ labels, int n,
                            int* __restrict__ pT) {        // [C][NB]
    __shared__ int h[NUM_CLASSES];
    const int mode32 = detect_mode32(labels);
    for (int i = threadIdx.x; i < NUM_CLASSES; i += blockDim.x) h[i] = 0;
    __syncthreads();
    const int base = blockIdx.x * HIST_CHUNK;
    for (int k = threadIdx.x; k < HIST_CHUNK; k += blockDim.x) {
        int i = base + k;
        if (i < n) atomicAdd(&h[get_label(labels, i, mode32)], 1);
    }
    __syncthreads();
    for (int c = threadIdx.x; c < NUM_CLASSES; c += blockDim.x)
        pT[c * NB + blockIdx.x] = h[c];
}

// ---------------- Kernel 2a: per-class prefix along blocks (wave per class) ----------------
__global__ __launch_bounds__(512) void scanA_kernel(int* __restrict__ pT,
                                                    int* __restrict__ totals) {
    const int wave = threadIdx.x >> 6;
    const int lane = threadIdx.x & 63;
    const int c = blockIdx.x * 8 + wave;        // 128 blocks x 8 waves = 1024
    int* p = pT + c * NB;
    const int v0 = p[2 * lane];
    const int v1 = p[2 * lane + 1];
    int s = v0 + v1;
    #pragma unroll
    for (int d = 1; d < 64; d <<= 1) {
        int t = __shfl_up(s, d, 64);
        if (lane >= d) s += t;
    }
    const int base = s - v0 - v1;
    p[2 * lane]     = base;
    p[2 * lane + 1] = base + v0;
    if (lane == 63) totals[c] = s;
}

// ---------------- Kernel 2b: cross-class exclusive scan (1 block) ----------------
__global__ void scanB_kernel(const int* __restrict__ totals,
                             int* __restrict__ offsets,
                             int* __restrict__ counts,
                             float* __restrict__ accum,
                             int* __restrict__ ticket) {
    __shared__ int tmp[NUM_CLASSES];
    const int c = threadIdx.x;                  // blockDim.x == 1024
    const int v = totals[c];
    tmp[c] = v;
    __syncthreads();
    for (int off = 1; off < NUM_CLASSES; off <<= 1) {
        int add = (c >= off) ? tmp[c - off] : 0;
        __syncthreads();
        tmp[c] += add;
        __syncthreads();
    }
    offsets[c] = tmp[c] - v;
    counts[c]  = v;
    if (c == 0) { accum[0] = 0.0f; accum[1] = 0.0f; *ticket = 0; }
}

// ---------------- Kernel 3: per-sample rank (coalesced write, LDS atomics) ----------------
__global__ void rank_kernel(const int* __restrict__ labels, int n,
                            const int* __restrict__ pT,
                            const int* __restrict__ offsets,
                            int* __restrict__ rank) {
    __shared__ int cur[NUM_CLASSES];
    const int mode32 = detect_mode32(labels);
    for (int c = threadIdx.x; c < NUM_CLASSES; c += blockDim.x)
        cur[c] = offsets[c] + pT[c * NB + blockIdx.x];
    __syncthreads();
    const int base = blockIdx.x * HIST_CHUNK;
    for (int k = threadIdx.x; k < HIST_CHUNK; k += blockDim.x) {
        int i = base + k;
        if (i < n)
            rank[i] = atomicAdd(&cur[get_label(labels, i, mode32)], 1);  // LDS atomic
    }
}

// ---------------- Kernel 4: sequential normalize + scatter-write bf16 ----------------
// 1024 blocks x 512 thr; block handles 256 consecutive rows. 16 lanes/row,
// 4 rows per wave-iteration. Reads fully coalesced; writes 256 B chunks at
// class-sorted position (fire-and-forget). Packed dim order is a fixed
// permutation of the original — fine, norms are permutation-invariant.
__global__ __launch_bounds__(512) void norm_scatter_kernel(
        const float* __restrict__ emb,      // N x 128 fp32
        const int* __restrict__ rank,
        uint4* __restrict__ nbuf,           // N rows x 256 B (16 x uint4)
        int n) {
    const int wave = threadIdx.x >> 6;
    const int lane = threadIdx.x & 63;
    const int g    = lane >> 4;
    const int sub  = lane & 15;
    const int base = blockIdx.x * 256;

    for (int r = wave * 4 + g; r < 256; r += 32) {
        const int row = base + r;
        if (row < n) {
            const float4* rp = (const float4*)(emb + (size_t)row * 128);
            float4 v0 = rp[sub];
            float4 v1 = rp[sub + 16];
            float sq = v0.x*v0.x + v0.y*v0.y + v0.z*v0.z + v0.w*v0.w
                     + v1.x*v1.x + v1.y*v1.y + v1.z*v1.z + v1.w*v1.w;
            sq += __shfl_xor(sq, 1, 64);
            sq += __shfl_xor(sq, 2, 64);
            sq += __shfl_xor(sq, 4, 64);
            sq += __shfl_xor(sq, 8, 64);
            float inv = 1.0f / fmaxf(sqrtf(sq), 1e-12f);
            uint4 w;
            w.x = packbf(v0.x * inv, v0.y * inv);
            w.y = packbf(v0.z * inv, v0.w * inv);
            w.z = packbf(v1.x * inv, v1.y * inv);
            w.w = packbf(v1.z * inv, v1.w * inv);
            const int pos = rank[row];
            nbuf[(size_t)pos * 16 + sub] = w;
        }
    }
}

// ---------------- Kernel 5: per-class CONTIGUOUS sum + loss (+finalize) ----------------
// One block (8 waves) per class; lane sub holds stored-dims [8*sub..8*sub+7].
// per_class = (count - ||sum of normalized rows||) / count.
#define WPB 8
__global__ __launch_bounds__(512) void class_sum2_kernel(
        const uint4* __restrict__ nbuf,
        const int* __restrict__ offsets,
        const int* __restrict__ counts,
        float* __restrict__ accum,          // [0]=loss_sum, [1]=n_valid
        int* __restrict__ ticket,
        float* __restrict__ out) {
    const int c     = blockIdx.x;
    const int start = offsets[c];
    const int count = counts[c];
    const int wave  = threadIdx.x >> 6;
    const int lane  = threadIdx.x & 63;
    const int g     = lane >> 4;
    const int sub   = lane & 15;

    float a[8];
    #pragma unroll
    for (int j = 0; j < 8; j++) a[j] = 0.0f;

    for (int r = wave * 4 + g; r < count; r += WPB * 4) {
        const uint4 w = nbuf[(size_t)(start + r) * 16 + sub];
        a[0] += unpack_lo(w.x); a[1] += unpack_hi(w.x);
        a[2] += unpack_lo(w.y); a[3] += unpack_hi(w.y);
        a[4] += unpack_lo(w.z); a[5] += unpack_hi(w.z);
        a[6] += unpack_lo(w.w); a[7] += unpack_hi(w.w);
    }

    __shared__ float s[WPB * 4][16][8];     // 16 KB
    {
        float* dst = s[wave * 4 + g][sub];
        #pragma unroll
        for (int j = 0; j < 8; j++) dst[j] = a[j];
    }
    __syncthreads();

    __shared__ float red[128];
    if (threadIdx.x < 128) {
        const int d  = threadIdx.x;         // stored-dim index
        const int sb = d >> 3;
        const int j  = d & 7;
        float t = 0.0f;
        #pragma unroll
        for (int k = 0; k < WPB * 4; k++) t += s[k][sb][j];
        red[d] = t * t;
    }
    __syncthreads();
    if (threadIdx.x < 64) {
        float x = red[threadIdx.x] + red[threadIdx.x + 64];
        #pragma unroll
        for (int off = 32; off; off >>= 1) x += __shfl_xor(x, off, 64);
        if (threadIdx.x == 0) {
            if (count >= 2) {
                float nrm = sqrtf(x);
                float per_class = ((float)count - nrm) / (float)count;
                atomicAdd(&accum[0], per_class);
                atomicAdd(&accum[1], 1.0f);
            }
            __threadfence();
            int old = atomicAdd(ticket, 1);
            if (old == NUM_CLASSES - 1) {
                float ls = atomicAdd(&accum[0], 0.0f);
                float nv = atomicAdd(&accum[1], 0.0f);
                out[0] = (nv > 0.0f) ? (ls / nv) : 0.0f;
            }
        }
    }
}

extern "C" void kernel_launch(void* const* d_in, const int* in_sizes, int n_in,
                              void* d_out, int out_size, void* d_ws, size_t ws_size,
                              hipStream_t stream) {
    const float* emb  = (const float*)d_in[0];
    const int* labels = (const int*)d_in[1];
    const int n = in_sizes[1];                   // 262144

    // Workspace layout (ws is 512 MiB; we use ~70 MB)
    char* ws = (char*)d_ws;
    int*   counts  = (int*)(ws + 0);                       // 1024 ints
    int*   offsets = (int*)(ws + 4096);                    // 1024 ints
    int*   totals  = (int*)(ws + 8192);                    // 1024 ints
    float* accum   = (float*)(ws + 12288);                 // 2 floats
    int*   ticket  = (int*)(ws + 12304);                   // 1 int
    int*   rank    = (int*)(ws + 16384);                   // n ints (1 MB)
    int*   pT      = (int*)(ws + 16384 + (size_t)n * 4);   // C*NB ints (512 KB)
    uint4* nbuf    = (uint4*)(ws + (2u << 20));            // n x 256 B (64 MB)

    const int normBlocks = (n + 255) / 256;                // 1024

    hist_kernel <<<NB, 256, 0, stream>>>(labels, n, pT);
    scanA_kernel<<<NB, 512, 0, stream>>>(pT, totals);
    scanB_kernel<<<1, NUM_CLASSES, 0, stream>>>(totals, offsets, counts, accum, ticket);
    rank_kernel <<<NB, 256, 0, stream>>>(labels, n, pT, offsets, rank);
    norm_scatter_kernel<<<normBlocks, 512, 0, stream>>>(emb, rank, nbuf, n);
    class_sum2_kernel<<<NUM_CLASSES, 512, 0, stream>>>(nbuf, offsets, counts,
                                                       accum, ticket, (float*)d_out);
}

// Round 7
// 260.755 us; speedup vs baseline: 1.0485x; 1.0485x over previous
//
#include <hip/hip_runtime.h>
#include <math.h>

// N=262144, D=128, C=1024. Embeddings fp32, output fp32 scalar, labels int32
// (int64 tolerated via uniform high-word probe). Pipeline: counting-sort
// (hist -> scanA -> scanB -> scatter) then one gather pass per class.
// class_sum is restructured for memory-level parallelism: 4 lanes/row, each
// lane issuing 8 independent float4 loads (R5's 1-load chain was the 95 us
// latency wall; R6's materialization traded it for worse volume).
#define NUM_CLASSES 1024
#define HIST_CHUNK 2048
#define NB 128                      // hist/scatter blocks

__device__ __forceinline__ int detect_mode32(const int* __restrict__ l) {
    return (l[1] | l[3] | l[5] | l[7] | l[9] | l[11] | l[13] | l[15]) != 0;
}
__device__ __forceinline__ int get_label(const int* __restrict__ l, int i, int mode32) {
    return l[mode32 ? i : (i << 1)] & (NUM_CLASSES - 1);
}

// ---------------- Kernel 1: per-block partial histograms ----------------
__global__ void hist_kernel(const int* __restrict__ labels, int n,
                            int* __restrict__ pT) {        // [C][NB]
    __shared__ int h[NUM_CLASSES];
    const int mode32 = detect_mode32(labels);
    for (int i = threadIdx.x; i < NUM_CLASSES; i += blockDim.x) h[i] = 0;
    __syncthreads();
    const int base = blockIdx.x * HIST_CHUNK;
    for (int k = threadIdx.x; k < HIST_CHUNK; k += blockDim.x) {
        int i = base + k;
        if (i < n) atomicAdd(&h[get_label(labels, i, mode32)], 1);
    }
    __syncthreads();
    for (int c = threadIdx.x; c < NUM_CLASSES; c += blockDim.x)
        pT[c * NB + blockIdx.x] = h[c];
}

// ---------------- Kernel 2a: per-class prefix along blocks (wave per class) ----------------
__global__ __launch_bounds__(512) void scanA_kernel(int* __restrict__ pT,
                                                    int* __restrict__ totals) {
    const int wave = threadIdx.x >> 6;
    const int lane = threadIdx.x & 63;
    const int c = blockIdx.x * 8 + wave;        // 128 blocks x 8 waves = 1024
    int* p = pT + c * NB;
    const int v0 = p[2 * lane];
    const int v1 = p[2 * lane + 1];
    int s = v0 + v1;
    #pragma unroll
    for (int d = 1; d < 64; d <<= 1) {
        int t = __shfl_up(s, d, 64);
        if (lane >= d) s += t;
    }
    const int base = s - v0 - v1;
    p[2 * lane]     = base;
    p[2 * lane + 1] = base + v0;
    if (lane == 63) totals[c] = s;
}

// ---------------- Kernel 2b: cross-class exclusive scan (1 block) ----------------
__global__ void scanB_kernel(const int* __restrict__ totals,
                             int* __restrict__ offsets,
                             int* __restrict__ counts,
                             float* __restrict__ accum,
                             int* __restrict__ ticket) {
    __shared__ int tmp[NUM_CLASSES];
    const int c = threadIdx.x;                  // blockDim.x == 1024
    const int v = totals[c];
    tmp[c] = v;
    __syncthreads();
    for (int off = 1; off < NUM_CLASSES; off <<= 1) {
        int add = (c >= off) ? tmp[c - off] : 0;
        __syncthreads();
        tmp[c] += add;
        __syncthreads();
    }
    offsets[c] = tmp[c] - v;
    counts[c]  = v;
    if (c == 0) { accum[0] = 0.0f; accum[1] = 0.0f; *ticket = 0; }
}

// ---------------- Kernel 3: scatter via LDS cursors (no global atomics) ----------------
__global__ void scatter_kernel(const int* __restrict__ labels, int n,
                               const int* __restrict__ pT,
                               const int* __restrict__ offsets,
                               int* __restrict__ sorted) {
    __shared__ int cur[NUM_CLASSES];
    const int mode32 = detect_mode32(labels);
    for (int c = threadIdx.x; c < NUM_CLASSES; c += blockDim.x)
        cur[c] = offsets[c] + pT[c * NB + blockIdx.x];
    __syncthreads();
    const int base = blockIdx.x * HIST_CHUNK;
    for (int k = threadIdx.x; k < HIST_CHUNK; k += blockDim.x) {
        int i = base + k;
        if (i < n) {
            int pos = atomicAdd(&cur[get_label(labels, i, mode32)], 1);  // LDS atomic
            sorted[pos] = i;
        }
    }
}

// ---------------- Kernel 4: per-class gather-sum + loss (+finalize) ----------------
// One block (8 waves) per class. 4 lanes per row: lane sub (0..3) covers dims
// [32*sub, 32*sub+32) as 8 independent float4 loads -> 8 outstanding
// loads/lane (vs 1 in R5, which was latency-bound at ~5.5 GB/s/CU).
// Wave handles 16 rows/iteration; ~2 iterations at count~256.
// Identity: sum_{i in c} dot(emb_i, proto_c) = ||sum_{i in c} norm(emb_i)||,
// so per_class = (count - ||sum||) / count. Last block (ticket) finalizes.
#define WPB 8
__global__ __launch_bounds__(512) void class_sum_kernel(
        const float* __restrict__ emb,      // N x 128 fp32
        const int* __restrict__ sorted,
        const int* __restrict__ offsets,
        const int* __restrict__ counts,
        float* __restrict__ accum,          // [0]=loss_sum, [1]=n_valid
        int* __restrict__ ticket,
        float* __restrict__ out) {
    const int c     = blockIdx.x;
    const int start = offsets[c];
    const int count = counts[c];
    const int wave  = threadIdx.x >> 6;
    const int lane  = threadIdx.x & 63;
    const int g     = lane >> 2;            // row-group 0..15 within wave
    const int sub   = lane & 3;             // dims [32*sub, 32*sub+32)

    float a[32];
    #pragma unroll
    for (int j = 0; j < 32; j++) a[j] = 0.0f;

    for (int r = wave * 16 + g; r < count; r += WPB * 16) {
        const int idx = sorted[start + r];
        const float4* rp = (const float4*)(emb + (size_t)idx * 128 + 32 * sub);
        float4 v[8];
        #pragma unroll
        for (int k = 0; k < 8; k++) v[k] = rp[k];      // 8 independent 16B loads
        float sq = 0.0f;
        #pragma unroll
        for (int k = 0; k < 8; k++)
            sq += v[k].x*v[k].x + v[k].y*v[k].y + v[k].z*v[k].z + v[k].w*v[k].w;
        sq += __shfl_xor(sq, 1, 64);                    // reduce over 4 lanes
        sq += __shfl_xor(sq, 2, 64);
        float inv = 1.0f / fmaxf(sqrtf(sq), 1e-12f);
        #pragma unroll
        for (int k = 0; k < 8; k++) {
            a[4*k+0] += v[k].x * inv;
            a[4*k+1] += v[k].y * inv;
            a[4*k+2] += v[k].z * inv;
            a[4*k+3] += v[k].w * inv;
        }
    }

    // Reduce over the 16 row-groups (strides 4..32): all lanes of equal sub
    // converge to the wave-total for dims [32*sub, 32*sub+32).
    #pragma unroll
    for (int d = 4; d < 64; d <<= 1) {
        #pragma unroll
        for (int j = 0; j < 32; j++) a[j] += __shfl_xor(a[j], d, 64);
    }

    __shared__ float sw[WPB][128];          // 4 KB
    if (g == 0) {
        #pragma unroll
        for (int j = 0; j < 32; j++) sw[wave][32 * sub + j] = a[j];
    }
    __syncthreads();

    __shared__ float red[128];
    if (threadIdx.x < 128) {
        float t = 0.0f;
        #pragma unroll
        for (int w = 0; w < WPB; w++) t += sw[w][threadIdx.x];
        red[threadIdx.x] = t * t;
    }
    __syncthreads();
    if (threadIdx.x < 64) {
        float x = red[threadIdx.x] + red[threadIdx.x + 64];
        #pragma unroll
        for (int off = 32; off; off >>= 1) x += __shfl_xor(x, off, 64);
        if (threadIdx.x == 0) {
            if (count >= 2) {
                float nrm = sqrtf(x);                   // = sum over class of sim
                float per_class = ((float)count - nrm) / (float)count;
                atomicAdd(&accum[0], per_class);
                atomicAdd(&accum[1], 1.0f);
            }
            __threadfence();
            int old = atomicAdd(ticket, 1);
            if (old == NUM_CLASSES - 1) {
                float ls = atomicAdd(&accum[0], 0.0f);  // device-scope reads
                float nv = atomicAdd(&accum[1], 0.0f);
                out[0] = (nv > 0.0f) ? (ls / nv) : 0.0f;
            }
        }
    }
}

extern "C" void kernel_launch(void* const* d_in, const int* in_sizes, int n_in,
                              void* d_out, int out_size, void* d_ws, size_t ws_size,
                              hipStream_t stream) {
    const float* emb  = (const float*)d_in[0];
    const int* labels = (const int*)d_in[1];
    const int n = in_sizes[1];                   // 262144

    // Workspace layout (~1.55 MB)
    char* ws = (char*)d_ws;
    int*   counts  = (int*)(ws + 0);                       // 1024 ints
    int*   offsets = (int*)(ws + 4096);                    // 1024 ints
    int*   totals  = (int*)(ws + 8192);                    // 1024 ints
    float* accum   = (float*)(ws + 12288);                 // 2 floats
    int*   ticket  = (int*)(ws + 12304);                   // 1 int
    int*   sorted  = (int*)(ws + 16384);                   // n ints (1 MB)
    int*   pT      = (int*)(ws + 16384 + (size_t)n * 4);   // C*NB ints (512 KB)

    hist_kernel <<<NB, 256, 0, stream>>>(labels, n, pT);
    scanA_kernel<<<NB, 512, 0, stream>>>(pT, totals);
    scanB_kernel<<<1, NUM_CLASSES, 0, stream>>>(totals, offsets, counts, accum, ticket);
    scatter_kernel<<<NB, 256, 0, stream>>>(labels, n, pT, offsets, sorted);
    class_sum_kernel<<<NUM_CLASSES, 512, 0, stream>>>(emb, sorted, offsets, counts,
                                                      accum, ticket, (float*)d_out);
}